// Round 1
// baseline (661.299 us; speedup 1.0000x reference)
//
#include <hip/hip_runtime.h>

#define H 64
#define G 64
#define OUT 2

// ---------------- degree ----------------
__global__ void k_init_deg(float* deg, int n) {
    int i = blockIdx.x * blockDim.x + threadIdx.x;
    if (i < n) deg[i] = 1.0f;  // self loop
}

__global__ void k_count_deg(const int* __restrict__ dst, float* __restrict__ deg, int e) {
    int i = blockIdx.x * blockDim.x + threadIdx.x;
    if (i < e) atomicAdd(&deg[dst[i]], 1.0f);
}

__global__ void k_rsqrt_inplace(float* deg, int n) {
    int i = blockIdx.x * blockDim.x + threadIdx.x;
    if (i < n) deg[i] = rsqrtf(deg[i]);  // deg buffer becomes dinv
}

// ---------------- 64x64 GEMM: Y[n,64] = X[n,64] @ W[64,64] ----------------
__global__ __launch_bounds__(256) void k_gemm64(const float* __restrict__ X,
                                                const float* __restrict__ W,
                                                float* __restrict__ Y, int n) {
    __shared__ float Ws[64][64];
    __shared__ float Xs[4][64];
    int tid = threadIdx.x;
    for (int i = tid; i < 64 * 64; i += 256) Ws[i >> 6][i & 63] = W[i];
    int r = tid >> 6;      // 0..3
    int c = tid & 63;      // 0..63
    int row = blockIdx.x * 4 + r;
    bool ok = (row < n);
    Xs[r][c] = ok ? X[(long long)row * 64 + c] : 0.0f;
    __syncthreads();
    float acc = 0.0f;
#pragma unroll
    for (int k = 0; k < 64; ++k) acc += Xs[r][k] * Ws[k][c];
    if (ok) Y[(long long)row * 64 + c] = acc;
}

// ---------------- agg init with self-loop term ----------------
__global__ void k_self_init(const float* __restrict__ h, const float* __restrict__ dinv,
                            float* __restrict__ agg, int n) {
    int i = blockIdx.x * blockDim.x + threadIdx.x;
    if (i < n * H) {
        int node = i >> 6;
        float d = dinv[node];
        agg[i] = h[i] * d * d;
    }
}

// ---------------- edge scatter: agg[dst] += h[src]*norm ----------------
__global__ __launch_bounds__(256) void k_scatter(const int* __restrict__ src,
                                                 const int* __restrict__ dst,
                                                 const float* __restrict__ dinv,
                                                 const float* __restrict__ h,
                                                 float* __restrict__ agg, int e) {
    int gid = blockIdx.x * blockDim.x + threadIdx.x;
    int edge = gid >> 6;
    int c = gid & 63;
    if (edge >= e) return;
    int s = src[edge];
    int d = dst[edge];
    float norm = dinv[s] * dinv[d];
    atomicAdd(&agg[(long long)d * H + c], h[(long long)s * H + c] * norm);
}

// ---------------- bias + relu (in place ok) ----------------
__global__ void k_bias_relu(const float* __restrict__ agg, const float* __restrict__ b,
                            float* __restrict__ h, int n) {
    int i = blockIdx.x * blockDim.x + threadIdx.x;
    if (i < n * H) {
        float v = agg[i] + b[i & 63];
        h[i] = v > 0.0f ? v : 0.0f;
    }
}

// ---------------- graph boundaries (batch is sorted) ----------------
__global__ void k_bounds(const int* __restrict__ batch, int* __restrict__ starts, int n) {
    int t = blockIdx.x * blockDim.x + threadIdx.x;
    if (t > G) return;
    if (t == G) { starts[G] = n; return; }
    int lo = 0, hi = n;
    while (lo < hi) {
        int mid = (lo + hi) >> 1;
        if (batch[mid] < t) lo = mid + 1; else hi = mid;
    }
    starts[t] = lo;
}

__global__ void k_zero(float* p, int n) {
    int i = blockIdx.x * blockDim.x + threadIdx.x;
    if (i < n) p[i] = 0.0f;
}

// ---------------- pool: pooled[g] = sum relu(agg2 + b2) over graph rows ----------------
#define NSPLIT 16
__global__ __launch_bounds__(64) void k_pool(const float* __restrict__ agg2,
                                             const float* __restrict__ b2,
                                             const int* __restrict__ starts,
                                             float* __restrict__ pooled) {
    int g = blockIdx.x / NSPLIT;
    int part = blockIdx.x % NSPLIT;
    int c = threadIdx.x;
    int s = starts[g], epos = starts[g + 1];
    int len = epos - s;
    if (len <= 0) return;
    int chunk = (len + NSPLIT - 1) / NSPLIT;
    int r0 = s + part * chunk;
    int r1 = min(r0 + chunk, epos);
    if (r0 >= r1) return;
    float b = b2[c];
    float acc = 0.0f;
    for (int r = r0; r < r1; ++r) {
        float v = agg2[(long long)r * H + c] + b;
        acc += v > 0.0f ? v : 0.0f;
    }
    atomicAdd(&pooled[g * H + c], acc);
}

// ---------------- final linear: out[g,o] = pooled[g]·Wlin[:,o] + gf[g]*Wlin[64,o] + blin[o] ----------------
__global__ void k_final(const float* __restrict__ pooled, const float* __restrict__ gf,
                        const float* __restrict__ Wlin, const float* __restrict__ blin,
                        float* __restrict__ out) {
    int t = threadIdx.x;
    if (t >= G * OUT) return;
    int g = t >> 1, o = t & 1;
    float acc = blin[o];
#pragma unroll
    for (int j = 0; j < 64; ++j) acc += pooled[g * H + j] * Wlin[j * OUT + o];
    acc += gf[g] * Wlin[64 * OUT + o];
    out[g * OUT + o] = acc;
}

extern "C" void kernel_launch(void* const* d_in, const int* in_sizes, int n_in,
                              void* d_out, int out_size, void* d_ws, size_t ws_size,
                              hipStream_t stream) {
    const float* x          = (const float*)d_in[0];
    const int*   edge_index = (const int*)d_in[1];
    const int*   batch      = (const int*)d_in[2];
    const float* gf         = (const float*)d_in[3];
    const float* W1         = (const float*)d_in[4];
    const float* b1         = (const float*)d_in[5];
    const float* W2         = (const float*)d_in[6];
    const float* b2         = (const float*)d_in[7];
    const float* Wlin       = (const float*)d_in[8];
    const float* blin       = (const float*)d_in[9];
    float* out = (float*)d_out;

    const int N = in_sizes[0] / H;
    const int E = in_sizes[1] / 2;
    const int* src = edge_index;
    const int* dst = edge_index + E;

    // workspace layout (floats)
    float* ws = (float*)d_ws;
    float* dinv   = ws;                    // N
    float* bufA   = dinv + N;              // N*H
    float* bufB   = bufA + (size_t)N * H;  // N*H
    float* pooled = bufB + (size_t)N * H;  // G*H
    int*   starts = (int*)(pooled + G * H); // G+1

    const int T = 256;

    // degrees -> dinv
    k_init_deg<<<(N + T - 1) / T, T, 0, stream>>>(dinv, N);
    k_count_deg<<<(E + T - 1) / T, T, 0, stream>>>(dst, dinv, E);
    k_rsqrt_inplace<<<(N + T - 1) / T, T, 0, stream>>>(dinv, N);

    // layer 1: h1 = x@W1 (bufA); agg1 (bufB)
    k_gemm64<<<(N + 3) / 4, T, 0, stream>>>(x, W1, bufA, N);
    k_self_init<<<((size_t)N * H + T - 1) / T, T, 0, stream>>>(bufA, dinv, bufB, N);
    k_scatter<<<((size_t)E * H + T - 1) / T, T, 0, stream>>>(src, dst, dinv, bufA, bufB, E);
    k_bias_relu<<<((size_t)N * H + T - 1) / T, T, 0, stream>>>(bufB, b1, bufB, N);

    // layer 2: h2 = h@W2 (bufA); agg2 (bufB, h no longer needed)
    k_gemm64<<<(N + 3) / 4, T, 0, stream>>>(bufB, W2, bufA, N);
    k_self_init<<<((size_t)N * H + T - 1) / T, T, 0, stream>>>(bufA, dinv, bufB, N);
    k_scatter<<<((size_t)E * H + T - 1) / T, T, 0, stream>>>(src, dst, dinv, bufA, bufB, E);

    // pooling (bias+relu fused)
    k_bounds<<<1, 128, 0, stream>>>(batch, starts, N);
    k_zero<<<(G * H + T - 1) / T, T, 0, stream>>>(pooled, G * H);
    k_pool<<<G * NSPLIT, 64, 0, stream>>>(bufB, b2, starts, pooled);

    // head
    k_final<<<1, 128, 0, stream>>>(pooled, gf, Wlin, blin, out);
}